// Round 1
// baseline (36630.414 us; speedup 1.0000x reference)
//
#include <hip/hip_runtime.h>
#include <hip/hip_bf16.h>
#include <cstdint>
#include <cstddef>

#define V_SZ 32000
#define E_SZ 512
#define U_SZ 1024
#define B_SZ 4
#define S_SZ 2048
#define NWG  128

typedef _Float16 f16;
typedef _Float16 f16x8 __attribute__((ext_vector_type(8)));
typedef _Float16 f16x4 __attribute__((ext_vector_type(4)));
typedef float    f32x4 __attribute__((ext_vector_type(4)));

__device__ __forceinline__ void async_copy16(const void* g, void* l) {
  __builtin_amdgcn_global_load_lds(
      (const __attribute__((address_space(1))) void*)g,
      (__attribute__((address_space(3))) void*)l, 16, 0, 0);
}

__device__ __forceinline__ f32x4 mfma16(f16x8 a, f16x8 b, f32x4 c) {
  return __builtin_amdgcn_mfma_f32_16x16x32_f16(a, b, c, 0, 0, 0);
}

// ---------------- embedding gather + hi/lo fp16 split ----------------
__global__ void k_gather_split(const int* __restrict__ inputs, const float* __restrict__ emb,
                               f16* __restrict__ x_hi, f16* __restrict__ x_lo) {
  int m = blockIdx.x;                  // 8192 rows, m = b*2048 + s
  int row = inputs[m];
  const float* src = emb + (size_t)row * E_SZ;
  int j = threadIdx.x * 4;
  f32x4 v = *(const f32x4*)(src + j);
  f16x4 hi, lo;
#pragma unroll
  for (int q = 0; q < 4; ++q) {
    f16 h = (f16)v[q];
    hi[q] = h;
    lo[q] = (f16)((v[q] - (float)h) * 4096.0f);
  }
  *(f16x4*)(x_hi + (size_t)m * E_SZ + j) = hi;
  *(f16x4*)(x_lo + (size_t)m * E_SZ + j) = lo;
}

// ---------------- transpose [K][N] fp32 -> [N][K] fp16 ----------------
__global__ void k_transpose_split(const float* __restrict__ W, f16* __restrict__ Wt,
                                  int K, int N) {
  __shared__ float tile[32][33];
  int tx = threadIdx.x & 31, ty = threadIdx.x >> 5;   // 32 x 8
  int n0 = blockIdx.x * 32, k0 = blockIdx.y * 32;
#pragma unroll
  for (int i = 0; i < 4; ++i)
    tile[ty + 8 * i][tx] = W[(size_t)(k0 + ty + 8 * i) * N + n0 + tx];
  __syncthreads();
#pragma unroll
  for (int i = 0; i < 4; ++i)
    Wt[(size_t)(n0 + ty + 8 * i) * K + k0 + tx] = (f16)tile[tx][ty + 8 * i];
}

// ---------------- fp16 2-pass GEMM: C = (Ah + Al/4096) @ Bt^T + bias ----------------
// A: [M][K] f16 (hi, lo*4096). Bt: [N][K] f16. C: fp32.
// Tile 128x128xBK32, 256 thr, 2x2 waves of 64x64. LDS linear dest + source-swizzled
// granules (kg ^= (r>>1)&3) so swizzled ds_read_b128 is ~2-way conflict (free).
template<int K, bool REMAP>
__global__ __launch_bounds__(256, 2)
void k_gemm2s(const f16* __restrict__ Ah, const f16* __restrict__ Al,
              const f16* __restrict__ Bt, const float* __restrict__ bias,
              float* __restrict__ C, int N) {
  __shared__ f16 lds[2][3 * 4096];     // 3 tiles x 512 granules x 8 halves, 24KB/buf
  const int tid = threadIdx.x;
  const int lane = tid & 63;
  const int wave = tid >> 6;
  const int wm = wave >> 1, wn = wave & 1;
  const int m0 = blockIdx.y * 128;
  const int n0 = blockIdx.x * 128;

  auto stage = [&](int buf, int kk) {
#pragma unroll
    for (int i = 0; i < 6; ++i) {
      int g = i * 256 + tid;           // 1536 granules: [0,512)=Ah [512,1024)=Al [1024,1536)=B
      int tile = g >> 9;
      int idx = g & 511;
      int r = idx >> 2;
      int kg = (idx & 3) ^ ((r >> 1) & 3);   // inverse-swizzled source
      const f16* src = (tile == 0) ? Ah : (tile == 1) ? Al : Bt;
      int row = (tile == 2) ? (n0 + r) : (m0 + r);
      const f16* gp = src + (size_t)row * K + kk + kg * 8;
      f16* lp = &lds[buf][(g & ~63) * 8];     // wave-uniform base; HW adds lane*16B
      async_copy16(gp, lp);
    }
  };

  f32x4 accH[4][4] = {};
  f32x4 accL[4][4] = {};

  stage(0, 0);
  int buf = 0;
  for (int kk = 0; kk < K; kk += 32) {
    __syncthreads();                   // drains vmcnt -> buf ready, prev compute done
    if (kk + 32 < K) stage(buf ^ 1, kk + 32);
    const f16* base = &lds[buf][0];
    const int kg = lane >> 4;
    f16x8 bfr[4];
#pragma unroll
    for (int fn = 0; fn < 4; ++fn) {
      int r = wn * 64 + fn * 16 + (lane & 15);
      bfr[fn] = *(const f16x8*)(base + 2 * 4096 + r * 32 + ((kg ^ ((r >> 1) & 3)) * 8));
    }
#pragma unroll
    for (int fm = 0; fm < 4; ++fm) {
      int r = wm * 64 + fm * 16 + (lane & 15);
      int off = r * 32 + ((kg ^ ((r >> 1) & 3)) * 8);
      f16x8 ah = *(const f16x8*)(base + off);
      f16x8 al = *(const f16x8*)(base + 4096 + off);
#pragma unroll
      for (int fn = 0; fn < 4; ++fn) {
        accH[fm][fn] = mfma16(ah, bfr[fn], accH[fm][fn]);
        accL[fm][fn] = mfma16(al, bfr[fn], accL[fm][fn]);
      }
    }
    buf ^= 1;
  }

  const float inv = 1.0f / 4096.0f;
#pragma unroll
  for (int fn = 0; fn < 4; ++fn) {
    int col = n0 + wn * 64 + fn * 16 + (lane & 15);
    float bv = bias[col];
#pragma unroll
    for (int fm = 0; fm < 4; ++fm) {
      int row0 = m0 + wm * 64 + fm * 16 + ((lane >> 4) << 2);
#pragma unroll
      for (int j = 0; j < 4; ++j) {
        int row = row0 + j;
        float v = accH[fm][fn][j] + inv * accL[fm][fn][j] + bv;
        size_t orow = REMAP ? ((size_t)(row & (S_SZ - 1)) * B_SZ + (row >> 11))
                            : (size_t)row;
        C[orow * (size_t)N + col] = v;
      }
    }
  }
}

// ---------------- persistent GRU recurrence ----------------
// 128 WGs, WG g owns h-cols [g*8, g*8+8). Wh slice fp32 col-major [24][1028] in LDS.
// Per step: poll per-WG release flags of step t-1, stage full h (16KB) from global,
// fp32 dots (wave w: cols 6w..6w+5, lanes k-strided x4 contiguous), butterfly reduce,
// gates in fp32, publish h slice + flag. hs written as fp16 hi + lo*4096 for the GEMM.
__global__ __launch_bounds__(256, 1)
void k_gru(const float* __restrict__ xg, const float* __restrict__ Wh,
           const float* __restrict__ bh, float* __restrict__ h_buf,
           unsigned int* __restrict__ flags,
           f16* __restrict__ hs_hi, f16* __restrict__ hs_lo) {
  __shared__ float Whs[24][1028];      // pad 1028: col starts 16B-aligned, reads conflict-free
  __shared__ float h_lds[4][1024];
  __shared__ float hg_sh[24][4];
  __shared__ float bh_s[24];

  const int g = blockIdx.x;
  const int tid = threadIdx.x;
  const int lane = tid & 63;
  const int wave = tid >> 6;
  const int u0 = g * 8;

  for (int idx = tid; idx < 24 * 1024; idx += 256) {
    int c = idx % 24;
    int k = idx / 24;
    Whs[c][k] = Wh[(size_t)k * 3072 + (c >> 3) * 1024 + u0 + (c & 7)];
  }
  if (tid < 24) bh_s[tid] = bh[(tid >> 3) * 1024 + u0 + (tid & 7)];
  __syncthreads();

  const int c0 = wave * 6;
  for (int t = 0; t < S_SZ; ++t) {
    // prefetch xg[t] (independent of h) before the wait
    float xz = 0.f, xr = 0.f, xh = 0.f;
    if (tid < 32) {
      int j = tid >> 2, b = tid & 3;
      size_t base = ((size_t)t * B_SZ + b) * 3072 + u0 + j;
      xz = xg[base];
      xr = xg[base + 1024];
      xh = xg[base + 2048];
    }
    if (t > 0 && wave == 0) {
      const unsigned int* fl = flags + (size_t)(t - 1) * NWG;
      while (true) {
        unsigned int a  = __hip_atomic_load(fl + lane,      __ATOMIC_RELAXED, __HIP_MEMORY_SCOPE_AGENT);
        unsigned int b2 = __hip_atomic_load(fl + 64 + lane, __ATOMIC_RELAXED, __HIP_MEMORY_SCOPE_AGENT);
        if (__all((a != 0) && (b2 != 0))) break;
        __builtin_amdgcn_s_sleep(1);
      }
    }
    __syncthreads();
    __threadfence();                   // acquire: make producers' h visible
    const float* hb = h_buf + (size_t)(t & 1) * (B_SZ * U_SZ);
#pragma unroll
    for (int i = 0; i < 4; ++i) {
      int idx = i * 256 + tid;
      *(f32x4*)(&h_lds[0][0] + idx * 4) = *(const f32x4*)(hb + idx * 4);
    }
    __syncthreads();

    float acc[6][4];
#pragma unroll
    for (int c = 0; c < 6; ++c)
#pragma unroll
      for (int b = 0; b < 4; ++b) acc[c][b] = 0.0f;

#pragma unroll
    for (int i = 0; i < 4; ++i) {
      int k4 = i * 256 + lane * 4;
      f32x4 h4[4], w4[6];
#pragma unroll
      for (int b = 0; b < 4; ++b) h4[b] = *(const f32x4*)(&h_lds[b][k4]);
#pragma unroll
      for (int c = 0; c < 6; ++c) w4[c] = *(const f32x4*)(&Whs[c0 + c][k4]);
#pragma unroll
      for (int c = 0; c < 6; ++c)
#pragma unroll
        for (int b = 0; b < 4; ++b)
#pragma unroll
          for (int q = 0; q < 4; ++q) acc[c][b] += w4[c][q] * h4[b][q];
    }
#pragma unroll
    for (int c = 0; c < 6; ++c)
#pragma unroll
      for (int b = 0; b < 4; ++b) {
        float v = acc[c][b];
#pragma unroll
        for (int off = 32; off >= 1; off >>= 1) v += __shfl_xor(v, off, 64);
        acc[c][b] = v;
      }
    if (lane < 24) hg_sh[c0 + (lane >> 2)][lane & 3] = acc[lane >> 2][lane & 3];
    __syncthreads();

    if (tid < 32) {
      int j = tid >> 2, b = tid & 3;
      float hz = hg_sh[j][b]      + bh_s[j];
      float hr = hg_sh[8 + j][b]  + bh_s[8 + j];
      float hh = hg_sh[16 + j][b] + bh_s[16 + j];
      float z  = 1.0f / (1.0f + expf(-(xz + hz)));
      float r  = 1.0f / (1.0f + expf(-(xr + hr)));
      float hc = tanhf(xh + r * hh);
      float hold = h_lds[b][u0 + j];
      float hnew = z * hold + (1.0f - z) * hc;
      h_buf[(size_t)((t + 1) & 1) * (B_SZ * U_SZ) + b * U_SZ + u0 + j] = hnew;
      f16 hi = (f16)hnew;
      size_t hidx = ((size_t)b * S_SZ + t) * U_SZ + u0 + j;
      hs_hi[hidx] = hi;
      hs_lo[hidx] = (f16)((hnew - (float)hi) * 4096.0f);
    }
    __syncthreads();
    if (tid == 0) {
      __threadfence();                 // release: flush slice before flag
      __hip_atomic_store(flags + (size_t)t * NWG + g, 1u,
                         __ATOMIC_RELAXED, __HIP_MEMORY_SCOPE_AGENT);
    }
  }
}

// ---------------- launch ----------------
extern "C" void kernel_launch(void* const* d_in, const int* in_sizes, int n_in,
                              void* d_out, int out_size, void* d_ws, size_t ws_size,
                              hipStream_t stream) {
  const int*   inputs = (const int*)d_in[0];
  const float* emb    = (const float*)d_in[1];
  const float* Wx     = (const float*)d_in[2];
  const float* Wh     = (const float*)d_in[3];
  const float* bx     = (const float*)d_in[4];
  const float* bh     = (const float*)d_in[5];
  const float* Wd     = (const float*)d_in[6];
  const float* bd     = (const float*)d_in[7];
  float* out = (float*)d_out;

  char* ws = (char*)d_ws;
  // layout (bytes), all 256-aligned
  f16*   x_hi  = (f16*)(ws + 0);            //  8,388,608
  f16*   x_lo  = (f16*)(ws + 8388608);      //  8,388,608
  f16*   Wx_t  = (f16*)(ws + 16777216);     //  3,145,728  [3072][512]
  f16*   Wd_t  = (f16*)(ws + 19922944);     // 65,536,000  [32000][1024]
  f16*   hs_hi = (f16*)(ws + 85458944);     // 16,777,216  [B*S][1024]
  f16*   hs_lo = (f16*)(ws + 102236160);    // 16,777,216
  float* xg    = (float*)(ws + 119013376);  // 100,663,296 [S][B][3072]
  float* h_buf = (float*)(ws + 219676672);  // 32,768      [2][4][1024]
  unsigned int* flags = (unsigned int*)(ws + 219709440);  // 1,048,576 [2048][128]

  // reset sync state every call (graph-replay safe)
  hipMemsetAsync(ws + 219676672, 0, 32768 + (size_t)S_SZ * NWG * 4, stream);

  k_gather_split<<<B_SZ * S_SZ, 128, 0, stream>>>(inputs, emb, x_hi, x_lo);
  k_transpose_split<<<dim3(3072 / 32, 512 / 32), 256, 0, stream>>>(Wx, Wx_t, 512, 3072);
  k_transpose_split<<<dim3(V_SZ / 32, 1024 / 32), 256, 0, stream>>>(Wd, Wd_t, 1024, V_SZ);
  k_gemm2s<512, true><<<dim3(3072 / 128, 8192 / 128), 256, 0, stream>>>(
      x_hi, x_lo, Wx_t, bx, xg, 3072);
  k_gru<<<NWG, 256, 0, stream>>>(xg, Wh, bh, h_buf, flags, hs_hi, hs_lo);
  k_gemm2s<1024, false><<<dim3(V_SZ / 128, 8192 / 128), 256, 0, stream>>>(
      hs_hi, hs_lo, Wd_t, bd, out, V_SZ);
}

// Round 2
// 14136.049 us; speedup vs baseline: 2.5913x; 2.5913x over previous
//
#include <hip/hip_runtime.h>
#include <hip/hip_bf16.h>
#include <cstdint>
#include <cstddef>

#define V_SZ 32000
#define E_SZ 512
#define U_SZ 1024
#define B_SZ 4
#define S_SZ 2048
#define NWG  128

typedef _Float16 f16;
typedef _Float16 f16x8 __attribute__((ext_vector_type(8)));
typedef _Float16 f16x4 __attribute__((ext_vector_type(4)));
typedef float    f32x4 __attribute__((ext_vector_type(4)));

__device__ __forceinline__ void async_copy16(const void* g, void* l) {
  __builtin_amdgcn_global_load_lds(
      (const __attribute__((address_space(1))) void*)g,
      (__attribute__((address_space(3))) void*)l, 16, 0, 0);
}

__device__ __forceinline__ f32x4 mfma16(f16x8 a, f16x8 b, f32x4 c) {
  return __builtin_amdgcn_mfma_f32_16x16x32_f16(a, b, c, 0, 0, 0);
}

// full-wave (64) sum via DPP; result valid in lane 63 only. Pure VALU (no LDS pipe).
__device__ __forceinline__ float wave_sum64(float v) {
  v += __int_as_float(__builtin_amdgcn_update_dpp(0, __float_as_int(v), 0x111, 0xf, 0xf, true)); // row_shr:1
  v += __int_as_float(__builtin_amdgcn_update_dpp(0, __float_as_int(v), 0x112, 0xf, 0xf, true)); // row_shr:2
  v += __int_as_float(__builtin_amdgcn_update_dpp(0, __float_as_int(v), 0x114, 0xf, 0xf, true)); // row_shr:4
  v += __int_as_float(__builtin_amdgcn_update_dpp(0, __float_as_int(v), 0x118, 0xf, 0xf, true)); // row_shr:8
  v += __int_as_float(__builtin_amdgcn_update_dpp(0, __float_as_int(v), 0x142, 0xa, 0xf, true)); // row_bcast:15
  v += __int_as_float(__builtin_amdgcn_update_dpp(0, __float_as_int(v), 0x143, 0xc, 0xf, true)); // row_bcast:31
  return v;
}

// ---------------- embedding gather + hi/lo fp16 split ----------------
__global__ void k_gather_split(const int* __restrict__ inputs, const float* __restrict__ emb,
                               f16* __restrict__ x_hi, f16* __restrict__ x_lo) {
  int m = blockIdx.x;                  // 8192 rows, m = b*2048 + s
  int row = inputs[m];
  const float* src = emb + (size_t)row * E_SZ;
  int j = threadIdx.x * 4;
  f32x4 v = *(const f32x4*)(src + j);
  f16x4 hi, lo;
#pragma unroll
  for (int q = 0; q < 4; ++q) {
    f16 h = (f16)v[q];
    hi[q] = h;
    lo[q] = (f16)((v[q] - (float)h) * 4096.0f);
  }
  *(f16x4*)(x_hi + (size_t)m * E_SZ + j) = hi;
  *(f16x4*)(x_lo + (size_t)m * E_SZ + j) = lo;
}

// ---------------- transpose [K][N] fp32 -> [N][K] fp16 ----------------
__global__ void k_transpose_split(const float* __restrict__ W, f16* __restrict__ Wt,
                                  int K, int N) {
  __shared__ float tile[32][33];
  int tx = threadIdx.x & 31, ty = threadIdx.x >> 5;   // 32 x 8
  int n0 = blockIdx.x * 32, k0 = blockIdx.y * 32;
#pragma unroll
  for (int i = 0; i < 4; ++i)
    tile[ty + 8 * i][tx] = W[(size_t)(k0 + ty + 8 * i) * N + n0 + tx];
  __syncthreads();
#pragma unroll
  for (int i = 0; i < 4; ++i)
    Wt[(size_t)(n0 + ty + 8 * i) * K + k0 + tx] = (f16)tile[tx][ty + 8 * i];
}

// ---------------- fp16 2-pass GEMM: C = (Ah + Al/4096) @ Bt^T + bias ----------------
template<int K, bool REMAP>
__global__ __launch_bounds__(256, 2)
void k_gemm2s(const f16* __restrict__ Ah, const f16* __restrict__ Al,
              const f16* __restrict__ Bt, const float* __restrict__ bias,
              float* __restrict__ C, int N) {
  __shared__ f16 lds[2][3 * 4096];     // 3 tiles x 512 granules x 8 halves, 24KB/buf
  const int tid = threadIdx.x;
  const int lane = tid & 63;
  const int wave = tid >> 6;
  const int wm = wave >> 1, wn = wave & 1;
  const int m0 = blockIdx.y * 128;
  const int n0 = blockIdx.x * 128;

  auto stage = [&](int buf, int kk) {
#pragma unroll
    for (int i = 0; i < 6; ++i) {
      int g = i * 256 + tid;           // 1536 granules: [0,512)=Ah [512,1024)=Al [1024,1536)=B
      int tile = g >> 9;
      int idx = g & 511;
      int r = idx >> 2;
      int kg = (idx & 3) ^ ((r >> 1) & 3);   // inverse-swizzled source
      const f16* src = (tile == 0) ? Ah : (tile == 1) ? Al : Bt;
      int row = (tile == 2) ? (n0 + r) : (m0 + r);
      const f16* gp = src + (size_t)row * K + kk + kg * 8;
      f16* lp = &lds[buf][(g & ~63) * 8];     // wave-uniform base; HW adds lane*16B
      async_copy16(gp, lp);
    }
  };

  f32x4 accH[4][4] = {};
  f32x4 accL[4][4] = {};

  stage(0, 0);
  int buf = 0;
  for (int kk = 0; kk < K; kk += 32) {
    __syncthreads();                   // drains vmcnt -> buf ready, prev compute done
    if (kk + 32 < K) stage(buf ^ 1, kk + 32);
    const f16* base = &lds[buf][0];
    const int kg = lane >> 4;
    f16x8 bfr[4];
#pragma unroll
    for (int fn = 0; fn < 4; ++fn) {
      int r = wn * 64 + fn * 16 + (lane & 15);
      bfr[fn] = *(const f16x8*)(base + 2 * 4096 + r * 32 + ((kg ^ ((r >> 1) & 3)) * 8));
    }
#pragma unroll
    for (int fm = 0; fm < 4; ++fm) {
      int r = wm * 64 + fm * 16 + (lane & 15);
      int off = r * 32 + ((kg ^ ((r >> 1) & 3)) * 8);
      f16x8 ah = *(const f16x8*)(base + off);
      f16x8 al = *(const f16x8*)(base + 4096 + off);
#pragma unroll
      for (int fn = 0; fn < 4; ++fn) {
        accH[fm][fn] = mfma16(ah, bfr[fn], accH[fm][fn]);
        accL[fm][fn] = mfma16(al, bfr[fn], accL[fm][fn]);
      }
    }
    buf ^= 1;
  }

  const float inv = 1.0f / 4096.0f;
#pragma unroll
  for (int fn = 0; fn < 4; ++fn) {
    int col = n0 + wn * 64 + fn * 16 + (lane & 15);
    float bv = bias[col];
#pragma unroll
    for (int fm = 0; fm < 4; ++fm) {
      int row0 = m0 + wm * 64 + fm * 16 + ((lane >> 4) << 2);
#pragma unroll
      for (int j = 0; j < 4; ++j) {
        int row = row0 + j;
        float v = accH[fm][fn][j] + inv * accL[fm][fn][j] + bv;
        size_t orow = REMAP ? ((size_t)(row & (S_SZ - 1)) * B_SZ + (row >> 11))
                            : (size_t)row;
        C[orow * (size_t)N + col] = v;
      }
    }
  }
}

// ---------------- persistent GRU recurrence (v2: fence-free, LDS-free hot path) ---
// 128 WGs, WG g owns h-cols [g*8, g*8+8). Wh slice lives in REGISTERS (96 VGPR/lane).
// Per step: all waves poll flags(t-1) (relaxed agent atomics, no fences); each lane
// loads its h k-slice straight from IC via sc0 sc1 loads into regs; pure-VALU dot;
// DPP wave reduce; ONE barrier (hg_sh handoff); gates in wave0 (hold in regs);
// publish h via sc0 sc1 stores + vmcnt(0) + relaxed flag.
__global__ __launch_bounds__(256, 1)
void k_gru(const float* __restrict__ xg, const float* __restrict__ Wh,
           const float* __restrict__ bh, float* __restrict__ h_buf,
           unsigned int* __restrict__ flags,
           f16* __restrict__ hs_hi, f16* __restrict__ hs_lo) {
  __shared__ float Whs[24][1028];      // preload staging only (not in per-step path)
  __shared__ float hg_sh[24][4];
  __shared__ float hnew_sh[4][8];
  __shared__ float bh_s[24];

  const int g = blockIdx.x;
  const int tid = threadIdx.x;
  const int lane = tid & 63;
  const int wave = tid >> 6;
  const int u0 = g * 8;

  // ---- stage Wh slice (cols {z,r,h}x[u0,u0+8)) into LDS, then into registers ----
  for (int idx = tid; idx < 24 * 1024; idx += 256) {
    int j = idx & 7;
    int k = (idx >> 3) & 1023;
    int gate = idx >> 13;
    Whs[gate * 8 + j][k] = Wh[(size_t)k * 3072 + gate * 1024 + u0 + j];
  }
  if (tid < 24) bh_s[tid] = bh[(tid >> 3) * 1024 + u0 + (tid & 7)];
  __syncthreads();

  const int c0 = wave * 6;
  f32x4 Wreg[6][4];                    // 96 VGPR: Wreg[c][i] = Whs[c0+c][i*256+lane*4 ..+3]
#pragma unroll
  for (int c = 0; c < 6; ++c)
#pragma unroll
    for (int i = 0; i < 4; ++i)
      Wreg[c][i] = *(const f32x4*)&Whs[c0 + c][i * 256 + lane * 4];
  __syncthreads();

  float hold = 0.0f;                   // own h value carried in-register (tid<32)

  for (int t = 0; t < S_SZ; ++t) {
    // prefetch xg[t] (independent of h) before the wait
    float xz = 0.f, xr = 0.f, xh = 0.f;
    if (tid < 32) {
      int j = tid >> 2, b = tid & 3;
      size_t base = ((size_t)t * B_SZ + b) * 3072 + u0 + j;
      xz = xg[base];
      xr = xg[base + 1024];
      xh = xg[base + 2048];
    }
    // all waves poll step t-1 flags (64 lanes x 2 packed flags)
    if (t > 0) {
      unsigned long long* fl = (unsigned long long*)flags + (size_t)(t - 1) * 64;
      while (true) {
        unsigned long long v = __hip_atomic_load(fl + lane, __ATOMIC_RELAXED,
                                                 __HIP_MEMORY_SCOPE_AGENT);
        if (__all(v == 0x0000000100000001ULL)) break;
        __builtin_amdgcn_s_sleep(1);
      }
    }
    // load h(t-1): each lane reads its k-slice (16 x f32x4) from IC, bypassing caches
    const float* hbF = h_buf + (size_t)(t & 1) * (B_SZ * U_SZ) + lane * 4;
    f32x4 hr[16];                      // hr[b*4+i] = h[b][i*256 + lane*4 ..+3]
    {
      const float* a0 = hbF;           // b=0 (+i*1024B imm offsets)
      const float* a1 = hbF + 1024;
      const float* a2 = hbF + 2048;
      const float* a3 = hbF + 3072;
      asm volatile(
        "global_load_dwordx4 %0, %16, off sc0 sc1\n\t"
        "global_load_dwordx4 %1, %16, off offset:1024 sc0 sc1\n\t"
        "global_load_dwordx4 %2, %16, off offset:2048 sc0 sc1\n\t"
        "global_load_dwordx4 %3, %16, off offset:3072 sc0 sc1\n\t"
        "global_load_dwordx4 %4, %17, off sc0 sc1\n\t"
        "global_load_dwordx4 %5, %17, off offset:1024 sc0 sc1\n\t"
        "global_load_dwordx4 %6, %17, off offset:2048 sc0 sc1\n\t"
        "global_load_dwordx4 %7, %17, off offset:3072 sc0 sc1\n\t"
        "global_load_dwordx4 %8, %18, off sc0 sc1\n\t"
        "global_load_dwordx4 %9, %18, off offset:1024 sc0 sc1\n\t"
        "global_load_dwordx4 %10, %18, off offset:2048 sc0 sc1\n\t"
        "global_load_dwordx4 %11, %18, off offset:3072 sc0 sc1\n\t"
        "global_load_dwordx4 %12, %19, off sc0 sc1\n\t"
        "global_load_dwordx4 %13, %19, off offset:1024 sc0 sc1\n\t"
        "global_load_dwordx4 %14, %19, off offset:2048 sc0 sc1\n\t"
        "global_load_dwordx4 %15, %19, off offset:3072 sc0 sc1\n\t"
        "s_waitcnt vmcnt(0)"
        : "=&v"(hr[0]), "=&v"(hr[1]), "=&v"(hr[2]), "=&v"(hr[3]),
          "=&v"(hr[4]), "=&v"(hr[5]), "=&v"(hr[6]), "=&v"(hr[7]),
          "=&v"(hr[8]), "=&v"(hr[9]), "=&v"(hr[10]), "=&v"(hr[11]),
          "=&v"(hr[12]), "=&v"(hr[13]), "=&v"(hr[14]), "=&v"(hr[15])
        : "v"(a0), "v"(a1), "v"(a2), "v"(a3)
        : "memory");
    }
    __builtin_amdgcn_sched_barrier(0);  // keep FMAs below the waitcnt (rule #18)

    // pure-VALU dot: acc[c][b] = partial over this lane's 16 k-values
    float acc[6][4];
#pragma unroll
    for (int c = 0; c < 6; ++c)
#pragma unroll
      for (int b = 0; b < 4; ++b) acc[c][b] = 0.0f;
#pragma unroll
    for (int i = 0; i < 4; ++i)
#pragma unroll
      for (int c = 0; c < 6; ++c)
#pragma unroll
        for (int b = 0; b < 4; ++b)
#pragma unroll
          for (int q = 0; q < 4; ++q)
            acc[c][b] += Wreg[c][i][q] * hr[b * 4 + i][q];

    // DPP wave reduction; lane 63 holds the full 1024-length dots
    f32x4 row[6];
#pragma unroll
    for (int c = 0; c < 6; ++c)
#pragma unroll
      for (int b = 0; b < 4; ++b) row[c][b] = wave_sum64(acc[c][b]);
    if (lane == 63) {
#pragma unroll
      for (int c = 0; c < 6; ++c) *(f32x4*)&hg_sh[c0 + c][0] = row[c];
    }
    __syncthreads();                   // the single per-step barrier (hg_sh handoff)

    if (tid < 32) {
      int j = tid >> 2, b = tid & 3;
      float hz = hg_sh[j][b]      + bh_s[j];
      float hrr = hg_sh[8 + j][b]  + bh_s[8 + j];
      float hh = hg_sh[16 + j][b] + bh_s[16 + j];
      float z  = 1.0f / (1.0f + expf(-(xz + hz)));
      float r  = 1.0f / (1.0f + expf(-(xr + hrr)));
      float hc = tanhf(xh + r * hh);
      float hnew = z * hold + (1.0f - z) * hc;
      hold = hnew;
      hnew_sh[b][j] = hnew;
      f16 hi = (f16)hnew;
      size_t hidx = ((size_t)b * S_SZ + t) * U_SZ + u0 + j;
      hs_hi[hidx] = hi;
      hs_lo[hidx] = (f16)((hnew - (float)hi) * 4096.0f);
    }
    if (tid < 8) {                     // publish own slice: write-through to IC
      int b = tid >> 1, hf = tid & 1;
      f32x4 v;
      v[0] = hnew_sh[b][hf * 4 + 0];
      v[1] = hnew_sh[b][hf * 4 + 1];
      v[2] = hnew_sh[b][hf * 4 + 2];
      v[3] = hnew_sh[b][hf * 4 + 3];
      float* dst = h_buf + (size_t)((t + 1) & 1) * (B_SZ * U_SZ) + b * U_SZ + u0 + hf * 4;
      asm volatile("global_store_dwordx4 %0, %1, off sc0 sc1" :: "v"(dst), "v"(v) : "memory");
    }
    if (tid == 0) {
      asm volatile("s_waitcnt vmcnt(0)" ::: "memory");   // h stores at IC before flag
      __hip_atomic_store(flags + (size_t)t * NWG + g, 1u,
                         __ATOMIC_RELAXED, __HIP_MEMORY_SCOPE_AGENT);
    }
    // no trailing barrier: waves 1-3 block on own flag in next poll; wave0 publishes
  }
}

// ---------------- launch ----------------
extern "C" void kernel_launch(void* const* d_in, const int* in_sizes, int n_in,
                              void* d_out, int out_size, void* d_ws, size_t ws_size,
                              hipStream_t stream) {
  const int*   inputs = (const int*)d_in[0];
  const float* emb    = (const float*)d_in[1];
  const float* Wx     = (const float*)d_in[2];
  const float* Wh     = (const float*)d_in[3];
  const float* bx     = (const float*)d_in[4];
  const float* bh     = (const float*)d_in[5];
  const float* Wd     = (const float*)d_in[6];
  const float* bd     = (const float*)d_in[7];
  float* out = (float*)d_out;

  char* ws = (char*)d_ws;
  // layout (bytes), all 256-aligned
  f16*   x_hi  = (f16*)(ws + 0);            //  8,388,608
  f16*   x_lo  = (f16*)(ws + 8388608);      //  8,388,608
  f16*   Wx_t  = (f16*)(ws + 16777216);     //  3,145,728  [3072][512]
  f16*   Wd_t  = (f16*)(ws + 19922944);     // 65,536,000  [32000][1024]
  f16*   hs_hi = (f16*)(ws + 85458944);     // 16,777,216  [B*S][1024]
  f16*   hs_lo = (f16*)(ws + 102236160);    // 16,777,216
  float* xg    = (float*)(ws + 119013376);  // 100,663,296 [S][B][3072]
  float* h_buf = (float*)(ws + 219676672);  // 32,768      [2][4][1024]
  unsigned int* flags = (unsigned int*)(ws + 219709440);  // 1,048,576 [2048][128]

  // reset sync state every call (graph-replay safe)
  hipMemsetAsync(ws + 219676672, 0, 32768 + (size_t)S_SZ * NWG * 4, stream);

  k_gather_split<<<B_SZ * S_SZ, 128, 0, stream>>>(inputs, emb, x_hi, x_lo);
  k_transpose_split<<<dim3(3072 / 32, 512 / 32), 256, 0, stream>>>(Wx, Wx_t, 512, 3072);
  k_transpose_split<<<dim3(V_SZ / 32, 1024 / 32), 256, 0, stream>>>(Wd, Wd_t, 1024, V_SZ);
  k_gemm2s<512, true><<<dim3(3072 / 128, 8192 / 128), 256, 0, stream>>>(
      x_hi, x_lo, Wx_t, bx, xg, 3072);
  k_gru<<<NWG, 256, 0, stream>>>(xg, Wh, bh, h_buf, flags, hs_hi, hs_lo);
  k_gemm2s<1024, false><<<dim3(V_SZ / 128, 8192 / 128), 256, 0, stream>>>(
      hs_hi, hs_lo, Wd_t, bd, out, V_SZ);
}

// Round 3
// 13271.973 us; speedup vs baseline: 2.7600x; 1.0651x over previous
//
#include <hip/hip_runtime.h>
#include <hip/hip_bf16.h>
#include <cstdint>
#include <cstddef>

#define V_SZ 32000
#define E_SZ 512
#define U_SZ 1024
#define B_SZ 4
#define S_SZ 2048
#define NWG  128

typedef _Float16 f16;
typedef _Float16 f16x8 __attribute__((ext_vector_type(8)));
typedef _Float16 f16x4 __attribute__((ext_vector_type(4)));
typedef float    f32x4 __attribute__((ext_vector_type(4)));

__device__ __forceinline__ void async_copy16(const void* g, void* l) {
  __builtin_amdgcn_global_load_lds(
      (const __attribute__((address_space(1))) void*)g,
      (__attribute__((address_space(3))) void*)l, 16, 0, 0);
}

__device__ __forceinline__ f32x4 mfma16(f16x8 a, f16x8 b, f32x4 c) {
  return __builtin_amdgcn_mfma_f32_16x16x32_f16(a, b, c, 0, 0, 0);
}

// full-wave (64) sum via DPP; result valid in lane 63 only. Pure VALU (no LDS pipe).
__device__ __forceinline__ float wave_sum64(float v) {
  v += __int_as_float(__builtin_amdgcn_update_dpp(0, __float_as_int(v), 0x111, 0xf, 0xf, true)); // row_shr:1
  v += __int_as_float(__builtin_amdgcn_update_dpp(0, __float_as_int(v), 0x112, 0xf, 0xf, true)); // row_shr:2
  v += __int_as_float(__builtin_amdgcn_update_dpp(0, __float_as_int(v), 0x114, 0xf, 0xf, true)); // row_shr:4
  v += __int_as_float(__builtin_amdgcn_update_dpp(0, __float_as_int(v), 0x118, 0xf, 0xf, true)); // row_shr:8
  v += __int_as_float(__builtin_amdgcn_update_dpp(0, __float_as_int(v), 0x142, 0xa, 0xf, true)); // row_bcast:15
  v += __int_as_float(__builtin_amdgcn_update_dpp(0, __float_as_int(v), 0x143, 0xc, 0xf, true)); // row_bcast:31
  return v;
}

// ---------------- embedding gather + hi/lo fp16 split ----------------
__global__ void k_gather_split(const int* __restrict__ inputs, const float* __restrict__ emb,
                               f16* __restrict__ x_hi, f16* __restrict__ x_lo) {
  int m = blockIdx.x;                  // 8192 rows, m = b*2048 + s
  int row = inputs[m];
  const float* src = emb + (size_t)row * E_SZ;
  int j = threadIdx.x * 4;
  f32x4 v = *(const f32x4*)(src + j);
  f16x4 hi, lo;
#pragma unroll
  for (int q = 0; q < 4; ++q) {
    f16 h = (f16)v[q];
    hi[q] = h;
    lo[q] = (f16)((v[q] - (float)h) * 4096.0f);
  }
  *(f16x4*)(x_hi + (size_t)m * E_SZ + j) = hi;
  *(f16x4*)(x_lo + (size_t)m * E_SZ + j) = lo;
}

// ---------------- transpose [K][N] fp32 -> [N][K] fp16 ----------------
__global__ void k_transpose_split(const float* __restrict__ W, f16* __restrict__ Wt,
                                  int K, int N) {
  __shared__ float tile[32][33];
  int tx = threadIdx.x & 31, ty = threadIdx.x >> 5;   // 32 x 8
  int n0 = blockIdx.x * 32, k0 = blockIdx.y * 32;
#pragma unroll
  for (int i = 0; i < 4; ++i)
    tile[ty + 8 * i][tx] = W[(size_t)(k0 + ty + 8 * i) * N + n0 + tx];
  __syncthreads();
#pragma unroll
  for (int i = 0; i < 4; ++i)
    Wt[(size_t)(n0 + ty + 8 * i) * K + k0 + tx] = (f16)tile[tx][ty + 8 * i];
}

// ---------------- fp16 2-pass GEMM: C = (Ah + Al/4096) @ Bt^T + bias ----------------
template<int K, bool REMAP>
__global__ __launch_bounds__(256, 2)
void k_gemm2s(const f16* __restrict__ Ah, const f16* __restrict__ Al,
              const f16* __restrict__ Bt, const float* __restrict__ bias,
              float* __restrict__ C, int N) {
  __shared__ f16 lds[2][3 * 4096];     // 3 tiles x 512 granules x 8 halves, 24KB/buf
  const int tid = threadIdx.x;
  const int lane = tid & 63;
  const int wave = tid >> 6;
  const int wm = wave >> 1, wn = wave & 1;
  const int m0 = blockIdx.y * 128;
  const int n0 = blockIdx.x * 128;

  auto stage = [&](int buf, int kk) {
#pragma unroll
    for (int i = 0; i < 6; ++i) {
      int g = i * 256 + tid;           // 1536 granules: [0,512)=Ah [512,1024)=Al [1024,1536)=B
      int tile = g >> 9;
      int idx = g & 511;
      int r = idx >> 2;
      int kg = (idx & 3) ^ ((r >> 1) & 3);   // inverse-swizzled source
      const f16* src = (tile == 0) ? Ah : (tile == 1) ? Al : Bt;
      int row = (tile == 2) ? (n0 + r) : (m0 + r);
      const f16* gp = src + (size_t)row * K + kk + kg * 8;
      f16* lp = &lds[buf][(g & ~63) * 8];     // wave-uniform base; HW adds lane*16B
      async_copy16(gp, lp);
    }
  };

  f32x4 accH[4][4] = {};
  f32x4 accL[4][4] = {};

  stage(0, 0);
  int buf = 0;
  for (int kk = 0; kk < K; kk += 32) {
    __syncthreads();                   // drains vmcnt -> buf ready, prev compute done
    if (kk + 32 < K) stage(buf ^ 1, kk + 32);
    const f16* base = &lds[buf][0];
    const int kg = lane >> 4;
    f16x8 bfr[4];
#pragma unroll
    for (int fn = 0; fn < 4; ++fn) {
      int r = wn * 64 + fn * 16 + (lane & 15);
      bfr[fn] = *(const f16x8*)(base + 2 * 4096 + r * 32 + ((kg ^ ((r >> 1) & 3)) * 8));
    }
#pragma unroll
    for (int fm = 0; fm < 4; ++fm) {
      int r = wm * 64 + fm * 16 + (lane & 15);
      int off = r * 32 + ((kg ^ ((r >> 1) & 3)) * 8);
      f16x8 ah = *(const f16x8*)(base + off);
      f16x8 al = *(const f16x8*)(base + 4096 + off);
#pragma unroll
      for (int fn = 0; fn < 4; ++fn) {
        accH[fm][fn] = mfma16(ah, bfr[fn], accH[fm][fn]);
        accL[fm][fn] = mfma16(al, bfr[fn], accL[fm][fn]);
      }
    }
    buf ^= 1;
  }

  const float inv = 1.0f / 4096.0f;
#pragma unroll
  for (int fn = 0; fn < 4; ++fn) {
    int col = n0 + wn * 64 + fn * 16 + (lane & 15);
    float bv = bias[col];
#pragma unroll
    for (int fm = 0; fm < 4; ++fm) {
      int row0 = m0 + wm * 64 + fm * 16 + ((lane >> 4) << 2);
#pragma unroll
      for (int j = 0; j < 4; ++j) {
        int row = row0 + j;
        float v = accH[fm][fn][j] + inv * accL[fm][fn][j] + bv;
        size_t orow = REMAP ? ((size_t)(row & (S_SZ - 1)) * B_SZ + (row >> 11))
                            : (size_t)row;
        C[orow * (size_t)N + col] = v;
      }
    }
  }
}

// ---------------- persistent GRU recurrence (v3: data-as-flag sentinel ring) ------
// Ring of 4 h-slots (h_ring[slot][b][u], fp32). Unwritten values = 0xFFFFFFFF (-NaN,
// impossible since |h|<1 strictly). Consumers poll their own k-slice with sc0 sc1
// loads; all-ordered => data is already in registers (detect == load, 1 RT).
// Producer just stores h (no ack wait, no flag). WG g re-poisons its slice of slot
// (t+3)&3 during step t; poison is drained by g's own next-step poll vmcnt(0) before
// g's next data store, and by the barrier argument no wave still reads that slot.
__global__ __launch_bounds__(256, 1)
void k_gru(const float* __restrict__ xg, const float* __restrict__ Wh,
           const float* __restrict__ bh, float* __restrict__ h_ring,
           f16* __restrict__ hs_hi, f16* __restrict__ hs_lo) {
  __shared__ float Whs[24][1028];      // preload staging only (not in per-step path)
  __shared__ float hg_sh[24][4];
  __shared__ float hnew_sh[4][8];
  __shared__ float bh_s[24];

  const int g = blockIdx.x;
  const int tid = threadIdx.x;
  const int lane = tid & 63;
  const int wave = tid >> 6;
  const int u0 = g * 8;

  // ---- stage Wh slice (cols {z,r,h}x[u0,u0+8)) into LDS, then into registers ----
  for (int idx = tid; idx < 24 * 1024; idx += 256) {
    int j = idx & 7;
    int k = (idx >> 3) & 1023;
    int gate = idx >> 13;
    Whs[gate * 8 + j][k] = Wh[(size_t)k * 3072 + gate * 1024 + u0 + j];
  }
  if (tid < 24) bh_s[tid] = bh[(tid >> 3) * 1024 + u0 + (tid & 7)];
  __syncthreads();

  const int c0 = wave * 6;
  f32x4 Wreg[6][4];                    // 96 VGPR: Wreg[c][i] = Whs[c0+c][i*256+lane*4 ..+3]
#pragma unroll
  for (int c = 0; c < 6; ++c)
#pragma unroll
    for (int i = 0; i < 4; ++i)
      Wreg[c][i] = *(const f32x4*)&Whs[c0 + c][i * 256 + lane * 4];
  __syncthreads();

  float hold = 0.0f;                   // own h value carried in-register (tid<32)
  f32x4 nanv;
  nanv[0] = nanv[1] = nanv[2] = nanv[3] = __int_as_float(0xFFFFFFFFu);

  for (int t = 0; t < S_SZ; ++t) {
    // prefetch xg[t] (independent of h) before the wait
    float xz = 0.f, xr = 0.f, xh = 0.f;
    if (tid < 32) {
      int j = tid >> 2, b = tid & 3;
      size_t base = ((size_t)t * B_SZ + b) * 3072 + u0 + j;
      xz = xg[base];
      xr = xg[base + 1024];
      xh = xg[base + 2048];
    }
    // poll own k-slice of ring slot t&3 (sc0 sc1 = IC-coherent); data IS the flag
    const float* hbF = h_ring + (size_t)(t & 3) * (B_SZ * U_SZ) + lane * 4;
    const float* a0 = hbF;
    const float* a1 = hbF + 1024;
    const float* a2 = hbF + 2048;
    const float* a3 = hbF + 3072;
    f32x4 hr[16];                      // hr[b*4+i] = h[b][i*256 + lane*4 ..+3]
    while (true) {
      asm volatile(
        "global_load_dwordx4 %0, %16, off sc0 sc1\n\t"
        "global_load_dwordx4 %1, %16, off offset:1024 sc0 sc1\n\t"
        "global_load_dwordx4 %2, %16, off offset:2048 sc0 sc1\n\t"
        "global_load_dwordx4 %3, %16, off offset:3072 sc0 sc1\n\t"
        "global_load_dwordx4 %4, %17, off sc0 sc1\n\t"
        "global_load_dwordx4 %5, %17, off offset:1024 sc0 sc1\n\t"
        "global_load_dwordx4 %6, %17, off offset:2048 sc0 sc1\n\t"
        "global_load_dwordx4 %7, %17, off offset:3072 sc0 sc1\n\t"
        "global_load_dwordx4 %8, %18, off sc0 sc1\n\t"
        "global_load_dwordx4 %9, %18, off offset:1024 sc0 sc1\n\t"
        "global_load_dwordx4 %10, %18, off offset:2048 sc0 sc1\n\t"
        "global_load_dwordx4 %11, %18, off offset:3072 sc0 sc1\n\t"
        "global_load_dwordx4 %12, %19, off sc0 sc1\n\t"
        "global_load_dwordx4 %13, %19, off offset:1024 sc0 sc1\n\t"
        "global_load_dwordx4 %14, %19, off offset:2048 sc0 sc1\n\t"
        "global_load_dwordx4 %15, %19, off offset:3072 sc0 sc1\n\t"
        "s_waitcnt vmcnt(0)"
        : "=&v"(hr[0]), "=&v"(hr[1]), "=&v"(hr[2]), "=&v"(hr[3]),
          "=&v"(hr[4]), "=&v"(hr[5]), "=&v"(hr[6]), "=&v"(hr[7]),
          "=&v"(hr[8]), "=&v"(hr[9]), "=&v"(hr[10]), "=&v"(hr[11]),
          "=&v"(hr[12]), "=&v"(hr[13]), "=&v"(hr[14]), "=&v"(hr[15])
        : "v"(a0), "v"(a1), "v"(a2), "v"(a3)
        : "memory");
      bool ok = true;
#pragma unroll
      for (int j = 0; j < 16; ++j) {
        ok = ok && !__builtin_isunordered(hr[j][0], hr[j][1]);
        ok = ok && !__builtin_isunordered(hr[j][2], hr[j][3]);
      }
      if (__all(ok)) break;
      __builtin_amdgcn_s_sleep(1);
    }
    __builtin_amdgcn_sched_barrier(0);  // keep FMAs below the waitcnt (rule #18)

    // pure-VALU dot: acc[c][b] = partial over this lane's 16 k-values
    float acc[6][4];
#pragma unroll
    for (int c = 0; c < 6; ++c)
#pragma unroll
      for (int b = 0; b < 4; ++b) acc[c][b] = 0.0f;
#pragma unroll
    for (int i = 0; i < 4; ++i)
#pragma unroll
      for (int c = 0; c < 6; ++c)
#pragma unroll
        for (int b = 0; b < 4; ++b)
#pragma unroll
          for (int q = 0; q < 4; ++q)
            acc[c][b] += Wreg[c][i][q] * hr[b * 4 + i][q];

    // DPP wave reduction; lane 63 holds the full 1024-length dots
    f32x4 row[6];
#pragma unroll
    for (int c = 0; c < 6; ++c)
#pragma unroll
      for (int b = 0; b < 4; ++b) row[c][b] = wave_sum64(acc[c][b]);
    if (lane == 63) {
#pragma unroll
      for (int c = 0; c < 6; ++c) *(f32x4*)&hg_sh[c0 + c][0] = row[c];
    }
    __syncthreads();                   // the single per-step barrier (hg_sh handoff)

    if (tid < 32) {
      int j = tid >> 2, b = tid & 3;
      float hz  = hg_sh[j][b]      + bh_s[j];
      float hrr = hg_sh[8 + j][b]  + bh_s[8 + j];
      float hh  = hg_sh[16 + j][b] + bh_s[16 + j];
      float z   = __builtin_amdgcn_rcpf(1.0f + __expf(-(xz + hz)));
      float r   = __builtin_amdgcn_rcpf(1.0f + __expf(-(xr + hrr)));
      float aa  = xh + r * hh;
      float e   = __expf(-2.0f * fabsf(aa));
      float hc  = copysignf((1.0f - e) * __builtin_amdgcn_rcpf(1.0f + e), aa);
      float hnew = z * hold + (1.0f - z) * hc;
      hold = hnew;
      hnew_sh[b][j] = hnew;
      f16 hi = (f16)hnew;
      size_t hidx = ((size_t)b * S_SZ + t) * U_SZ + u0 + j;
      hs_hi[hidx] = hi;
      hs_lo[hidx] = (f16)((hnew - (float)hi) * 4096.0f);
    }
    if (tid < 8) {                     // publish own slice to slot (t+1)&3 (data IS flag)
      int b = tid >> 1, hf = tid & 1;
      f32x4 v;
      v[0] = hnew_sh[b][hf * 4 + 0];
      v[1] = hnew_sh[b][hf * 4 + 1];
      v[2] = hnew_sh[b][hf * 4 + 2];
      v[3] = hnew_sh[b][hf * 4 + 3];
      float* dst = h_ring + (size_t)((t + 1) & 3) * (B_SZ * U_SZ) + b * U_SZ + u0 + hf * 4;
      asm volatile("global_store_dwordx4 %0, %1, off sc0 sc1" :: "v"(dst), "v"(v) : "memory");
    } else if (tid < 16) {             // re-poison own slice of slot (t+3)&3 (holds S_{t-1})
      int p = tid - 8;
      int b = p >> 1, hf = p & 1;
      float* dst = h_ring + (size_t)((t + 3) & 3) * (B_SZ * U_SZ) + b * U_SZ + u0 + hf * 4;
      asm volatile("global_store_dwordx4 %0, %1, off sc0 sc1" :: "v"(dst), "v"(nanv) : "memory");
    }
    // no ack wait, no flag: next iteration's poll vmcnt(0) drains these stores,
    // guaranteeing poison visibility before the NEXT data store to that slot.
  }
}

// ---------------- launch ----------------
extern "C" void kernel_launch(void* const* d_in, const int* in_sizes, int n_in,
                              void* d_out, int out_size, void* d_ws, size_t ws_size,
                              hipStream_t stream) {
  const int*   inputs = (const int*)d_in[0];
  const float* emb    = (const float*)d_in[1];
  const float* Wx     = (const float*)d_in[2];
  const float* Wh     = (const float*)d_in[3];
  const float* bx     = (const float*)d_in[4];
  const float* bh     = (const float*)d_in[5];
  const float* Wd     = (const float*)d_in[6];
  const float* bd     = (const float*)d_in[7];
  float* out = (float*)d_out;

  char* ws = (char*)d_ws;
  // layout (bytes), all 256-aligned
  f16*   x_hi  = (f16*)(ws + 0);            //  8,388,608
  f16*   x_lo  = (f16*)(ws + 8388608);      //  8,388,608
  f16*   Wx_t  = (f16*)(ws + 16777216);     //  3,145,728  [3072][512]
  f16*   Wd_t  = (f16*)(ws + 19922944);     // 65,536,000  [32000][1024]
  f16*   hs_hi = (f16*)(ws + 85458944);     // 16,777,216  [B*S][1024]
  f16*   hs_lo = (f16*)(ws + 102236160);    // 16,777,216
  float* xg    = (float*)(ws + 119013376);  // 100,663,296 [S][B][3072]
  float* h_ring = (float*)(ws + 219676672); // 65,536      [4][4][1024]

  // ring init every call (graph-replay safe): slot0 = S_0 = zeros, slots 1-3 = -NaN
  hipMemsetAsync(ws + 219676672, 0x00, 16384, stream);
  hipMemsetAsync(ws + 219676672 + 16384, 0xFF, 49152, stream);

  k_gather_split<<<B_SZ * S_SZ, 128, 0, stream>>>(inputs, emb, x_hi, x_lo);
  k_transpose_split<<<dim3(3072 / 32, 512 / 32), 256, 0, stream>>>(Wx, Wx_t, 512, 3072);
  k_transpose_split<<<dim3(V_SZ / 32, 1024 / 32), 256, 0, stream>>>(Wd, Wd_t, 1024, V_SZ);
  k_gemm2s<512, true><<<dim3(3072 / 128, 8192 / 128), 256, 0, stream>>>(
      x_hi, x_lo, Wx_t, bx, xg, 3072);
  k_gru<<<NWG, 256, 0, stream>>>(xg, Wh, bh, h_ring, hs_hi, hs_lo);
  k_gemm2s<1024, false><<<dim3(V_SZ / 128, 8192 / 128), 256, 0, stream>>>(
      hs_hi, hs_lo, Wd_t, bd, out, V_SZ);
}